// Round 5
// baseline (223.326 us; speedup 1.0000x reference)
//
#include <hip/hip_runtime.h>

// 3D spatial transformer (trilinear warp), voxelmorph semantics.
// vol: [B=2, X=160, Y=192, Z=160, C=1] fp32
// trf: [B=2, X=160, Y=192, Z=160, 3]  fp32 (dense displacement)
// out: same shape as vol, fp32.
//
// R5: (a) padded LDS z-stride 28 (bank = -4*iy+4*zq mix, not bank=iz) to cut
// the 4.7x bank-conflict factor; (b) 3-phase compute (addrs -> 32 ds_reads ->
// blend) so LDS latency is covered by ILP, not per-j serialized; (c) staging
// via float4 + ds_write_b128 (padding breaks global_load_lds contiguity).

#define NXD 160
#define NYD 192
#define NZD 160
#define NVOX (NXD * NYD * NZD)
#define NBATCH 2

#define TXT 8
#define TYT 16
#define TZT 16

#define LXS 16            // staged x extent (lox = x0t - 4)
#define LYS 24            // staged y extent (loy = y0t - 4)
#define LZS 24            // staged z values (loz = z0t - 4)
#define LZP 28            // padded z stride (28*4B = 112B, 16B-aligned rows)
#define LDS_N (LXS * LYS * LZP)   // 10752 floats = 42 KB

#define TILES_X (NXD / TXT)   // 20
#define TILES_Y (NYD / TYT)   // 12
#define TILES_Z (NZD / TZT)   // 10
#define NBLOCKS (NBATCH * TILES_X * TILES_Y * TILES_Z)   // 4800

typedef float f4 __attribute__((ext_vector_type(4)));

__global__ __launch_bounds__(512, 6)
void warp3d_kernel(const float* __restrict__ vol,
                   const float* __restrict__ trf,
                   float* __restrict__ out) {
    __shared__ float tile[LDS_N];

    int bid = blockIdx.x;
    int tz = bid % TILES_Z;
    int r  = bid / TILES_Z;
    int ty = r % TILES_Y;
    int r2 = r / TILES_Y;
    int tx = r2 % TILES_X;
    int b  = r2 / TILES_X;

    int x0t = tx * TXT, y0t = ty * TYT, z0t = tz * TZT;
    int lox = x0t - 4, loy = y0t - 4, loz = z0t - 4;

    const float* vb = vol + (size_t)b * NVOX;
    int t = threadIdx.x;

    // compute-phase voxel quad: 4 z-consecutive voxels per thread
    int zq = t & 3, yq = (t >> 2) & 15, xq = t >> 6;
    int x = x0t + xq, y = y0t + yq, zb0 = z0t + zq * 4;
    size_t vox_i = (((size_t)b * NXD + x) * NYD + y) * NZD + zb0;

    // prefetch trf (12 floats = 3 aligned float4) — overlaps staging
    const f4* trfv = (const f4*)(trf + vox_i * 3);
    f4 t0 = trfv[0], t1 = trfv[1], t2 = trfv[2];

    // ---- stage vol tile into LDS (padded z-stride) ----
    bool interior = (lox >= 0) & (lox + LXS <= NXD) &
                    (loy >= 0) & (loy + LYS <= NYD) &
                    (loz >= 0) & (loz + LZS <= NZD);
    if (interior) {
        // loz = z0t-4 is a multiple of 4 -> every row start is 16B-aligned.
        const float* gbase = vb + ((size_t)(lox * NYD + loy) * NZD + loz);
#pragma unroll
        for (int it = 0; it < 5; ++it) {
            int c = it * 512 + t;                 // float4 chunk id
            if (c < LXS * LYS * (LZS / 4)) {      // 2304
                int z4  = (c % 6) * 4;            // 6 chunks per z-line
                int row = c / 6;                  // 0..383
                int yi  = row % LYS;
                int xi  = row / LYS;
                f4 v = *(const f4*)(gbase + (size_t)xi * (NYD * NZD) + yi * NZD + z4);
                *(f4*)&tile[(xi * LYS + yi) * LZP + z4] = v;
            }
        }
    } else {
#pragma unroll 3
        for (int it = 0; it < 18; ++it) {         // 18*512 = 9216 = LXS*LYS*LZS
            int e = it * 512 + t;
            int zi  = e % LZS;
            int row = e / LZS;
            int yi  = row % LYS;
            int xi  = row / LYS;
            int gx = min(max(lox + xi, 0), NXD - 1);
            int gy = min(max(loy + yi, 0), NYD - 1);
            int gz = min(max(loz + zi, 0), NZD - 1);
            tile[(xi * LYS + yi) * LZP + zi] = vb[(size_t)(gx * NYD + gy) * NZD + gz];
        }
    }
    __syncthreads();

    float dxa[4] = {t0.x, t0.w, t1.z, t2.y};
    float dya[4] = {t0.y, t1.x, t1.w, t2.z};
    float dza[4] = {t0.z, t1.y, t2.x, t2.w};

    // ---- phase A: addresses + weights for all 4 voxels ----
    float wx0a[4], wy0a[4], wz0a[4];
    int abase[4], pack[4];
#pragma unroll
    for (int j = 0; j < 4; ++j) {
        float lx = fminf(fmaxf((float)x + dxa[j], 0.0f), (float)(NXD - 1));
        float ly = fminf(fmaxf((float)y + dya[j], 0.0f), (float)(NYD - 1));
        float lz = fminf(fmaxf((float)(zb0 + j) + dza[j], 0.0f), (float)(NZD - 1));
        float fx = floorf(lx), fy = floorf(ly), fz = floorf(lz);
        int x0 = (int)fx, y0 = (int)fy, z0 = (int)fz;
        // lower-corner weights d1 = loc1 - loc (0 at clamped top border)
        wx0a[j] = fminf(fx + 1.0f, (float)(NXD - 1)) - lx;
        wy0a[j] = fminf(fy + 1.0f, (float)(NYD - 1)) - ly;
        wz0a[j] = fminf(fz + 1.0f, (float)(NZD - 1)) - lz;

        int ix = x0 - lox, iy = y0 - loy, iz = z0 - loz;
        bool ok = ((unsigned)ix <= LXS - 2) & ((unsigned)iy <= LYS - 2) &
                  ((unsigned)iz <= LZS - 2);
        abase[j] = ok ? ((ix * LYS + iy) * LZP + iz) : 0;
        pack[j]  = ok ? -1 : (x0 | (y0 << 8) | (z0 << 16));   // all < 256
    }

    // ---- phase B: issue all 32 LDS reads ----
    float g[4][8];
#pragma unroll
    for (int j = 0; j < 4; ++j) {
        int a = abase[j];
        g[j][0] = tile[a];                   g[j][1] = tile[a + 1];
        g[j][2] = tile[a + LZP];             g[j][3] = tile[a + LZP + 1];
        g[j][4] = tile[a + LYS * LZP];       g[j][5] = tile[a + LYS * LZP + 1];
        g[j][6] = tile[a + LYS * LZP + LZP]; g[j][7] = tile[a + LYS * LZP + LZP + 1];
    }

    // ---- phase C: rare fallback + blend ----
    float res[4];
#pragma unroll
    for (int j = 0; j < 4; ++j) {
        float v000 = g[j][0], v001 = g[j][1], v010 = g[j][2], v011 = g[j][3];
        float v100 = g[j][4], v101 = g[j][5], v110 = g[j][6], v111 = g[j][7];

        if (pack[j] != -1) {   // rare: sample outside staged tile
            int x0 = pack[j] & 255, y0 = (pack[j] >> 8) & 255, z0 = (pack[j] >> 16) & 255;
            int x1 = min(x0 + 1, NXD - 1);
            int y1 = min(y0 + 1, NYD - 1);
            int z1 = min(z0 + 1, NZD - 1);
            size_t o00 = (size_t)(x0 * NYD + y0) * NZD;
            size_t o01 = (size_t)(x0 * NYD + y1) * NZD;
            size_t o10 = (size_t)(x1 * NYD + y0) * NZD;
            size_t o11 = (size_t)(x1 * NYD + y1) * NZD;
            v000 = vb[o00 + z0]; v001 = vb[o00 + z1];
            v010 = vb[o01 + z0]; v011 = vb[o01 + z1];
            v100 = vb[o10 + z0]; v101 = vb[o10 + z1];
            v110 = vb[o11 + z0]; v111 = vb[o11 + z1];
        }

        float wx0 = wx0a[j], wy0 = wy0a[j], wz0 = wz0a[j];
        float wx1 = 1.0f - wx0, wy1 = 1.0f - wy0, wz1 = 1.0f - wz0;
        res[j] = wx0 * (wy0 * (wz0 * v000 + wz1 * v001) +
                        wy1 * (wz0 * v010 + wz1 * v011)) +
                 wx1 * (wy0 * (wz0 * v100 + wz1 * v101) +
                        wy1 * (wz0 * v110 + wz1 * v111));
    }

    f4 o;
    o.x = res[0]; o.y = res[1]; o.z = res[2]; o.w = res[3];
    *(f4*)(out + vox_i) = o;
}

extern "C" void kernel_launch(void* const* d_in, const int* in_sizes, int n_in,
                              void* d_out, int out_size, void* d_ws, size_t ws_size,
                              hipStream_t stream) {
    const float* vol = (const float*)d_in[0];
    const float* trf = (const float*)d_in[1];
    float* out = (float*)d_out;

    warp3d_kernel<<<NBLOCKS, 512, 0, stream>>>(vol, trf, out);
}